// Round 7
// baseline (362.468 us; speedup 1.0000x reference)
//
#include <hip/hip_runtime.h>

#define NT 4096          // time samples per column
#define NCOL 4096        // 512 traces * 8 channels
#define EPT 64           // elements per lane: one wave sorts one whole column
#define BLOCK 512        // 8 waves: waves 0-3 pred cols w, waves 4-7 obs cols w
#define NBLOCKS 1024     // 4096 cols / 4 cols per block

__device__ __forceinline__ float b2f(int i) { return __builtin_bit_cast(float, i); }
__device__ __forceinline__ int   f2b(float f) { return __builtin_bit_cast(int, f); }

// Cross-lane fetch of partner lane^XM's value. MUST run at full exec:
// DPP/swizzle source lanes with EXEC=0 return 0 (bound_ctrl=1).
// XM 1,2,3 (quad_perm), 7 (row_half_mirror), 8 (row_ror:8), 15 (row_mirror): DPP,
// VALU pipe, zero DS traffic. XM 4,16,31: ds_swizzle. XM 63: ds_bpermute.
template <int XM>
__device__ __forceinline__ float lx(float v) {
    const int i = f2b(v);
    int r;
    if constexpr (XM == 1)       r = __builtin_amdgcn_update_dpp(0, i, 0xB1,  0xF, 0xF, true);
    else if constexpr (XM == 2)  r = __builtin_amdgcn_update_dpp(0, i, 0x4E,  0xF, 0xF, true);
    else if constexpr (XM == 3)  r = __builtin_amdgcn_update_dpp(0, i, 0x1B,  0xF, 0xF, true);
    else if constexpr (XM == 7)  r = __builtin_amdgcn_update_dpp(0, i, 0x141, 0xF, 0xF, true);
    else if constexpr (XM == 8)  r = __builtin_amdgcn_update_dpp(0, i, 0x128, 0xF, 0xF, true);
    else if constexpr (XM == 15) r = __builtin_amdgcn_update_dpp(0, i, 0x140, 0xF, 0xF, true);
    else if constexpr (XM == 4)  r = __builtin_amdgcn_ds_swizzle(i, 0x101F);
    else if constexpr (XM == 16) r = __builtin_amdgcn_ds_swizzle(i, 0x401F);
    else if constexpr (XM == 31) r = __builtin_amdgcn_ds_swizzle(i, 0x7C1F);
    else {
        const int lane = (int)(threadIdx.x & 63);
        r = __builtin_amdgcn_ds_bpermute((lane ^ XM) << 2, i);
    }
    return b2f(r);
}

__device__ __forceinline__ void cemin(float& a, float& b) {
    const float lo = fminf(a, b);
    const float hi = fmaxf(a, b);
    a = lo; b = hi;
}

// plain cross-lane stage, lane-xor M, same element index.
// km = (L&M)==0 is lane-uniform for the whole stage, so instead of
// per-element cmp+cndmask (2 VALU), prefetch partner values at FULL exec
// (chunk of 16), then one divergent if/else whose arms are pure v_min/v_max
// (1 VALU/elem, exec-masked). 192 -> 128 ops per DPP stage.
template <int M>
__device__ __forceinline__ void plain_stage(float (&x)[EPT], int L) {
    const bool km = (L & M) == 0;
    #pragma unroll
    for (int c = 0; c < EPT; c += 16) {
        float y[16];
        #pragma unroll
        for (int i = 0; i < 16; ++i) y[i] = lx<M>(x[c + i]);
        if (km) {
            #pragma unroll
            for (int i = 0; i < 16; ++i) x[c + i] = fminf(x[c + i], y[i]);
        } else {
            #pragma unroll
            for (int i = 0; i < 16; ++i) x[c + i] = fmaxf(x[c + i], y[i]);
        }
    }
}

template <int M>
__device__ __forceinline__ void plains_down(float (&x)[EPT], int L) {
    plain_stage<M>(x, L);
    if constexpr (M > 1) plains_down<M / 2>(x, L);
}

// intra-thread plain stages j = 32..1, all ascending (normalized network)
__device__ __forceinline__ void tail32(float (&x)[EPT]) {
    #pragma unroll
    for (int j = 32; j >= 1; j >>= 1) {
        #pragma unroll
        for (int e = 0; e < EPT; ++e)
            if ((e & j) == 0) cemin(x[e], x[e | j]);
    }
}

// Normalized bitonic merge of size k = 64*K (K = 2..64), fully in-wave:
// reversal: partner lane L^(K-1), element mirror e<->63-e, keep-min if (L&K/2)==0;
// then plain lane-xor stages m=K/4..1; then intra-thread tail j=32..1.
// Reversal uses the same full-exec-prefetch + masked min/max arms.
template <int K>
__device__ __forceinline__ void cross_merge(float (&x)[EPT], int L) {
    const bool km = (L & (K >> 1)) == 0;
    #pragma unroll
    for (int c = 0; c < EPT / 2; c += 8) {
        float ylo[8], yhi[8];
        #pragma unroll
        for (int i = 0; i < 8; ++i) {
            ylo[i] = lx<K - 1>(x[EPT - 1 - (c + i)]);   // partner's mirrored element
            yhi[i] = lx<K - 1>(x[c + i]);
        }
        if (km) {
            #pragma unroll
            for (int i = 0; i < 8; ++i) {
                x[c + i]            = fminf(x[c + i], ylo[i]);
                x[EPT - 1 - (c + i)] = fminf(x[EPT - 1 - (c + i)], yhi[i]);
            }
        } else {
            #pragma unroll
            for (int i = 0; i < 8; ++i) {
                x[c + i]            = fmaxf(x[c + i], ylo[i]);
                x[EPT - 1 - (c + i)] = fmaxf(x[EPT - 1 - (c + i)], yhi[i]);
            }
        }
    }
    if constexpr (K >= 4) plains_down<K / 4>(x, L);
    tail32(x);
}

// LDS (one union, phases sequential):
//   staging: 2 halves x 4 cols x 1024-word chunk regions = 8192 words (32 KB)
//   epilogue strips: 4 cols x 64 lanes x 33 words        = 8448 words (33 KB)
#define LS_WORDS 8448

__global__ __launch_bounds__(512, 4) void wass_kernel(const float* __restrict__ pred,
                                                      const float* __restrict__ obs,
                                                      float* __restrict__ out) {
    __shared__ __align__(16) float ls[LS_WORDS];

    const int bid  = blockIdx.x;
    const int cb   = (bid & 7) * 128 + (bid >> 3);   // XCD-band col-block swizzle
    const int col0 = cb * 4;

    const int t    = threadIdx.x;
    const int half = t >> 8;           // 0 = pred, 1 = obs
    const int ht   = t & 255;          // thread within half
    const int w    = (t >> 6) & 3;     // column (0..3) this wave sorts
    const int L    = t & 63;           // lane

    const float* __restrict__ src = half ? obs : pred;

    // ---- staged load + transpose: 4 chunks of 1024 rows ----
    // Per (half, col): 1024-word region, word(lr) = (lr&~31)|((lr&31)^((lr>>5)&15)).
    // chunk q holds rows r = b*64 + q*16 + s  (lr = b*16 + s).
    // Writer thread ht owns lr = 4*ht+j  -> bank (4(ht&7)+j)^((ht>>3)&15): 2-way, free.
    // Reader lane L reads lr = L*16+s    -> bank 16(L&1)+(s^((L>>1)&15)): 2-way, free.
    float x[EPT];
    {
        float* stg = ls + half * 4096;
        #pragma unroll
        for (int q = 0; q < 4; ++q) {
            #pragma unroll
            for (int j = 0; j < 4; ++j) {
                const int lr = (ht << 2) | j;                      // 0..1023
                const int r  = (lr >> 4) * 64 + q * 16 + (lr & 15);
                const float4 v = *(const float4*)&src[(size_t)r * NCOL + col0];
                const int wd = (lr & ~31) | ((lr & 31) ^ ((lr >> 5) & 15));
                stg[wd]        = v.x;      // column col0
                stg[1024 + wd] = v.y;      // column col0+1
                stg[2048 + wd] = v.z;      // column col0+2
                stg[3072 + wd] = v.w;      // column col0+3
            }
            __syncthreads();
            #pragma unroll
            for (int s = 0; s < 16; ++s) {
                const int lr = L * 16 + s;
                const int wd = (lr & ~31) | ((lr & 31) ^ ((lr >> 5) & 15));
                x[q * 16 + s] = stg[w * 1024 + wd];
            }
            __syncthreads();
        }
    }

    // ---- phase 1: normalized bitonic sort of my 64 contiguous elements ----
    #pragma unroll
    for (int k = 2; k <= 64; k <<= 1) {
        #pragma unroll
        for (int base = 0; base < EPT; base += k) {
            #pragma unroll
            for (int o = 0; o < k / 2; ++o)
                cemin(x[base + o], x[base + k - 1 - o]);
        }
        #pragma unroll
        for (int j = k / 4; j >= 1; j >>= 1) {
            #pragma unroll
            for (int e = 0; e < EPT; ++e)
                if ((e & j) == 0) cemin(x[e], x[e | j]);
        }
    }

    // ---- phase 2: merges k = 128..4096, all in-wave, no barriers ----
    cross_merge<2>(x, L);
    cross_merge<4>(x, L);
    cross_merge<8>(x, L);
    cross_merge<16>(x, L);
    cross_merge<32>(x, L);
    cross_merge<64>(x, L);

    // ---- epilogue: two 32-element passes, scalar stride-33 strips.
    // bank = (L+e)&31 for both write and read: 2-way, free. ----
    __syncthreads();                   // staging region is dead; safe to reuse
    const int sb = (w * 64 + L) * 33;
    float s = 0.0f;
    #pragma unroll
    for (int hh = 0; hh < 2; ++hh) {
        if (half == 0) {
            #pragma unroll
            for (int e = 0; e < 32; ++e)
                ls[sb + e] = x[hh * 32 + e];
        }
        __syncthreads();
        if (half == 1) {
            #pragma unroll
            for (int e = 0; e < 32; ++e)
                s += fabsf(x[hh * 32 + e] - ls[sb + e]);
        }
        __syncthreads();
    }
    if (half == 1) {
        #pragma unroll
        for (int off = 32; off > 0; off >>= 1)
            s += __shfl_down(s, off, 64);
        if (L == 0)
            atomicAdd(out, s * (1.0f / ((float)NT * (float)NCOL)));
    }
}

extern "C" void kernel_launch(void* const* d_in, const int* in_sizes, int n_in,
                              void* d_out, int out_size, void* d_ws, size_t ws_size,
                              hipStream_t stream) {
    const float* pred = (const float*)d_in[0];
    const float* obs  = (const float*)d_in[1];
    float* out = (float*)d_out;
    hipMemsetAsync(out, 0, sizeof(float), stream);
    wass_kernel<<<NBLOCKS, BLOCK, 0, stream>>>(pred, obs, out);
}

// Round 8
// 286.156 us; speedup vs baseline: 1.2667x; 1.2667x over previous
//
#include <hip/hip_runtime.h>

#define NT 4096          // time samples per column
#define NCOL 4096        // 512 traces * 8 channels
#define EPT 64           // elements per lane: one wave sorts one whole column
#define BLOCK 512        // 8 waves: waves 0-3 pred cols w, waves 4-7 obs cols w
#define NBLOCKS 1024     // 4096 cols / 4 cols per block

__device__ __forceinline__ float b2f(int i) { return __builtin_bit_cast(float, i); }
__device__ __forceinline__ int   f2b(float f) { return __builtin_bit_cast(int, f); }

// Cross-lane fetch of partner lane^XM's value (full exec always).
// XM 1,2,3 (quad_perm), 7 (row_half_mirror), 8 (row_ror:8), 15 (row_mirror): DPP,
// VALU pipe, zero DS traffic. XM 4,16,31: ds_swizzle. XM 63: ds_bpermute.
template <int XM>
__device__ __forceinline__ float lx(float v) {
    const int i = f2b(v);
    int r;
    if constexpr (XM == 1)       r = __builtin_amdgcn_update_dpp(0, i, 0xB1,  0xF, 0xF, true);
    else if constexpr (XM == 2)  r = __builtin_amdgcn_update_dpp(0, i, 0x4E,  0xF, 0xF, true);
    else if constexpr (XM == 3)  r = __builtin_amdgcn_update_dpp(0, i, 0x1B,  0xF, 0xF, true);
    else if constexpr (XM == 7)  r = __builtin_amdgcn_update_dpp(0, i, 0x141, 0xF, 0xF, true);
    else if constexpr (XM == 8)  r = __builtin_amdgcn_update_dpp(0, i, 0x128, 0xF, 0xF, true);
    else if constexpr (XM == 15) r = __builtin_amdgcn_update_dpp(0, i, 0x140, 0xF, 0xF, true);
    else if constexpr (XM == 4)  r = __builtin_amdgcn_ds_swizzle(i, 0x101F);
    else if constexpr (XM == 16) r = __builtin_amdgcn_ds_swizzle(i, 0x401F);
    else if constexpr (XM == 31) r = __builtin_amdgcn_ds_swizzle(i, 0x7C1F);
    else {
        const int lane = (int)(threadIdx.x & 63);
        r = __builtin_amdgcn_ds_bpermute((lane ^ XM) << 2, i);
    }
    return b2f(r);
}

__device__ __forceinline__ void cemin(float& a, float& b) {
    const float lo = fminf(a, b);
    const float hi = fmaxf(a, b);
    a = lo; b = hi;
}

// ---- SIGN-STORE flag-free cross-lane network ----
// Lane L stores v = x ^ s where s = dom<M>(L) encodes its keep-min(+)/keep-max(-)
// role for the current stage mask M. XOR-partners always have opposite roles, so
// EVERY cross CE for EVERY lane is the single flagless op  v = min(v, -fetch(v)):
//   s=0     : min(x, x_p)            (keep-min)
//   s=sign  : min(-x,-x_p) = -max()  (keep-max, stored form)
// No v_cmp / v_cndmask anywhere in the sort -> no VCC/SGPR flag serialization.
template <int M>
__device__ __forceinline__ unsigned dom(int L) {
    return (L & M) ? 0x80000000u : 0u;
}

// plain stage with mask M, entering from domain FROM: one v_xor (domain shift)
// + one fused v_min_dpp per element, all in-place (zero extra live temps).
template <int FROM, int M>
__device__ __forceinline__ void plains_down_s(float (&x)[EPT], int L) {
    const int D = (int)(dom<FROM>(L) ^ dom<M>(L));
    #pragma unroll
    for (int e = 0; e < EPT; ++e) x[e] = b2f(f2b(x[e]) ^ D);
    #pragma unroll
    for (int e = 0; e < EPT; ++e) x[e] = fminf(x[e], -lx<M>(x[e]));
    if constexpr (M > 1) plains_down_s<M, M / 2>(x, L);
}

// intra-thread plain stages j = 32..1, all ascending (true domain, flag-free)
__device__ __forceinline__ void tail32(float (&x)[EPT]) {
    #pragma unroll
    for (int j = 32; j >= 1; j >>= 1) {
        #pragma unroll
        for (int e = 0; e < EPT; ++e)
            if ((e & j) == 0) cemin(x[e], x[e | j]);
    }
}

// Normalized bitonic merge of size k = 64*K (K = 2..64), fully in-wave:
// enter stored domain (bit K/2 of L), reversal = 1 min_dpp/elem, plain stages
// with per-stage domain shifts, exit to true domain, intra tail.
template <int K>
__device__ __forceinline__ void cross_merge_s(float (&x)[EPT], int L) {
    const int Din = (int)dom<(K >> 1)>(L);
    #pragma unroll
    for (int e = 0; e < EPT; ++e) x[e] = b2f(f2b(x[e]) ^ Din);
    // reversal: partner lane L^(K-1), element mirror e<->63-e. Fetches of a
    // mirrored pair complete before either write (program order within the
    // iteration), matching the original ylo/yhi structure.
    #pragma unroll
    for (int c = 0; c < EPT / 2; ++c) {
        const float flo = lx<K - 1>(x[EPT - 1 - c]);
        const float fhi = lx<K - 1>(x[c]);
        x[c]           = fminf(x[c],           -flo);
        x[EPT - 1 - c] = fminf(x[EPT - 1 - c], -fhi);
    }
    if constexpr (K >= 4) plains_down_s<(K >> 1), (K >> 2)>(x, L);
    // exit: last stored domain is always dom<1> (K=2: rev domain = bit0 too)
    const int Dout = (int)dom<1>(L);
    #pragma unroll
    for (int e = 0; e < EPT; ++e) x[e] = b2f(f2b(x[e]) ^ Dout);
    tail32(x);
}

// LDS (one union, phases sequential):
//   staging: 2 halves x 4 cols x 1024-word chunk regions = 8192 words (32 KB)
//   epilogue strips: 4 cols x 64 lanes x 33 words        = 8448 words (33 KB)
#define LS_WORDS 8448

__global__ __launch_bounds__(512, 4) void wass_kernel(const float* __restrict__ pred,
                                                      const float* __restrict__ obs,
                                                      float* __restrict__ out) {
    __shared__ __align__(16) float ls[LS_WORDS];

    const int bid  = blockIdx.x;
    const int cb   = (bid & 7) * 128 + (bid >> 3);   // XCD-band col-block swizzle
    const int col0 = cb * 4;

    const int t    = threadIdx.x;
    const int half = t >> 8;           // 0 = pred, 1 = obs
    const int ht   = t & 255;          // thread within half
    const int w    = (t >> 6) & 3;     // column (0..3) this wave sorts
    const int L    = t & 63;           // lane

    const float* __restrict__ src = half ? obs : pred;

    // ---- staged load + transpose: 4 chunks of 1024 rows (R4-verified) ----
    // Per (half, col): 1024-word region, word(lr) = (lr&~31)|((lr&31)^((lr>>5)&15)).
    // Writer thread ht owns lr = 4*ht+j; reader lane L reads lr = L*16+s.
    // Both are exactly 2-way bank aliased = free.
    float x[EPT];
    {
        float* stg = ls + half * 4096;
        #pragma unroll
        for (int q = 0; q < 4; ++q) {
            #pragma unroll
            for (int j = 0; j < 4; ++j) {
                const int lr = (ht << 2) | j;                      // 0..1023
                const int r  = (lr >> 4) * 64 + q * 16 + (lr & 15);
                const float4 v = *(const float4*)&src[(size_t)r * NCOL + col0];
                const int wd = (lr & ~31) | ((lr & 31) ^ ((lr >> 5) & 15));
                stg[wd]        = v.x;      // column col0
                stg[1024 + wd] = v.y;      // column col0+1
                stg[2048 + wd] = v.z;      // column col0+2
                stg[3072 + wd] = v.w;      // column col0+3
            }
            __syncthreads();
            #pragma unroll
            for (int s = 0; s < 16; ++s) {
                const int lr = L * 16 + s;
                const int wd = (lr & ~31) | ((lr & 31) ^ ((lr >> 5) & 15));
                x[q * 16 + s] = stg[w * 1024 + wd];
            }
            __syncthreads();
        }
    }

    // ---- phase 1: normalized bitonic sort of my 64 contiguous elements ----
    // (intra-lane, flag-free min/max, true domain)
    #pragma unroll
    for (int k = 2; k <= 64; k <<= 1) {
        #pragma unroll
        for (int base = 0; base < EPT; base += k) {
            #pragma unroll
            for (int o = 0; o < k / 2; ++o)
                cemin(x[base + o], x[base + k - 1 - o]);
        }
        #pragma unroll
        for (int j = k / 4; j >= 1; j >>= 1) {
            #pragma unroll
            for (int e = 0; e < EPT; ++e)
                if ((e & j) == 0) cemin(x[e], x[e | j]);
        }
    }

    // ---- phase 2: merges k = 128..4096, all in-wave, no barriers, no flags ----
    cross_merge_s<2>(x, L);
    cross_merge_s<4>(x, L);
    cross_merge_s<8>(x, L);
    cross_merge_s<16>(x, L);
    cross_merge_s<32>(x, L);
    cross_merge_s<64>(x, L);

    // ---- epilogue: two 32-element passes, scalar stride-33 strips.
    // bank = (L+e)&31 for both write and read: 2-way, free. ----
    __syncthreads();                   // staging region is dead; safe to reuse
    const int sb = (w * 64 + L) * 33;
    float s = 0.0f;
    #pragma unroll
    for (int hh = 0; hh < 2; ++hh) {
        if (half == 0) {
            #pragma unroll
            for (int e = 0; e < 32; ++e)
                ls[sb + e] = x[hh * 32 + e];
        }
        __syncthreads();
        if (half == 1) {
            #pragma unroll
            for (int e = 0; e < 32; ++e)
                s += fabsf(x[hh * 32 + e] - ls[sb + e]);
        }
        __syncthreads();
    }
    if (half == 1) {
        #pragma unroll
        for (int off = 32; off > 0; off >>= 1)
            s += __shfl_down(s, off, 64);
        if (L == 0)
            atomicAdd(out, s * (1.0f / ((float)NT * (float)NCOL)));
    }
}

extern "C" void kernel_launch(void* const* d_in, const int* in_sizes, int n_in,
                              void* d_out, int out_size, void* d_ws, size_t ws_size,
                              hipStream_t stream) {
    const float* pred = (const float*)d_in[0];
    const float* obs  = (const float*)d_in[1];
    float* out = (float*)d_out;
    hipMemsetAsync(out, 0, sizeof(float), stream);
    wass_kernel<<<NBLOCKS, BLOCK, 0, stream>>>(pred, obs, out);
}